// Round 13
// baseline (454.731 us; speedup 1.0000x reference)
//
#include <hip/hip_runtime.h>

// MomentumSSM B=2, L=4096, D=512, N=16, R=32, P=64 — ONE fused kernel, NCH=128.
// R13: all 5 phases in one plain launch; grid-wide sync via manual atomic
// barrier (512 blocks == exactly 2/CU co-resident: __launch_bounds__(256,2)
// caps VGPR<=256 -> 2 waves/SIMD; LDS 8KB. Same mechanism as ROCm grid.sync).
// Fusion deletes: 4 dispatch gaps, dth array, scan2 re-reads of x/proj
// (dtv/xs live in registers, proj chunk lives in LDS from P2 to P4).
//
// Phases:  P0 W->bf16 split | P1 proj MFMA bf16x3 | P2 dt + zero-init chunk
// scan (fp16 state out) | P3 serial fix over 128 chunks | P4 final scan -> out
//
// v_t = beta*v + alpha*inp ; h_t = a_t*h + v ; a_t = exp(dt*A_n)
// chunk map: h_end = Pa*H0 + cv*V0 + hhat ; v_end = beta^LCH*V0 + vhat

#define D_IN 512
#define D_ST 16
#define DTR  32
#define BSZ  2
#define LSEQ 4096
#define PDIM 64
#define NCH  128
#define LCH  (LSEQ / NCH)  // 32
#define NBLK 512
#define LOG2E 1.44269504f
#define LN2   0.69314718f

typedef __attribute__((ext_vector_type(8))) short short8;
typedef __attribute__((ext_vector_type(4))) float f32x4;
typedef _Float16 f16;
typedef __attribute__((ext_vector_type(8))) _Float16 f16x8;

__device__ inline float fast_exp2(float x) { return __builtin_amdgcn_exp2f(x); }
__device__ inline float fast_log2(float x) { return __builtin_amdgcn_logf(x); }

__device__ inline unsigned short bf16_rne(float f) {
  unsigned b = __float_as_uint(f);
  return (unsigned short)((b + 0x7fffu + ((b >> 16) & 1u)) >> 16);
}

__device__ inline void cvt8(const float4 u, const float4 v, short8& hi, short8& lo) {
  float f[8] = {u.x, u.y, u.z, u.w, v.x, v.y, v.z, v.w};
#pragma unroll
  for (int i = 0; i < 8; ++i) {
    unsigned short h = bf16_rne(f[i]);
    hi[i] = (short)h;
    float r = f[i] - __uint_as_float((unsigned)h << 16);
    lo[i] = (short)bf16_rne(r);
  }
}

__device__ inline void st16h(f16* p, const float* s) {
  f16 t[16];
#pragma unroll
  for (int i = 0; i < 16; ++i) t[i] = (f16)s[i];
  *(f16x8*)p = *(f16x8*)&t[0];
  *(f16x8*)(p + 8) = *(f16x8*)&t[8];
}
__device__ inline void ld16h(const f16* p, float* d) {
  f16x8 a = *(const f16x8*)p;
  f16x8 b = *(const f16x8*)(p + 8);
#pragma unroll
  for (int i = 0; i < 8; ++i) { d[i] = (float)a[i]; d[8 + i] = (float)b[i]; }
}

__device__ inline bool loadA2(const float* A_log, int d, float* A2) {
  const float4* ap = (const float4*)(A_log + (size_t)d * D_ST);
#pragma unroll
  for (int i = 0; i < 4; ++i) {
    float4 a4 = ap[i];
    A2[4 * i + 0] = -__expf(a4.x) * LOG2E;
    A2[4 * i + 1] = -__expf(a4.y) * LOG2E;
    A2[4 * i + 2] = -__expf(a4.z) * LOG2E;
    A2[4 * i + 3] = -__expf(a4.w) * LOG2E;
  }
  bool pw = true;
#pragma unroll
  for (int n = 1; n < 16; ++n) {
    float ref = (float)(n + 1) * A2[0];
    pw = pw && (fabsf(A2[n] - ref) <= 2e-5f * fabsf(ref));
  }
  return pw;
}

// manual grid barrier: all NBLK blocks resident by construction.
__device__ inline void gbar(unsigned* cnt, unsigned target) {
  __syncthreads();
  if (threadIdx.x == 0) {
    __threadfence();  // release: drain + make prior writes device-visible
    __hip_atomic_fetch_add(cnt, 1u, __ATOMIC_RELEASE, __HIP_MEMORY_SCOPE_AGENT);
    while (__hip_atomic_load(cnt, __ATOMIC_ACQUIRE, __HIP_MEMORY_SCOPE_AGENT) < target) {
      __builtin_amdgcn_s_sleep(2);
    }
    __threadfence();  // acquire: invalidate caches before reading others' data
  }
  __syncthreads();
}

#define MM3(ACC, AH, AL, BH, BL)                                        \
  ACC = __builtin_amdgcn_mfma_f32_16x16x32_bf16(AL, BH, ACC, 0, 0, 0);  \
  ACC = __builtin_amdgcn_mfma_f32_16x16x32_bf16(AH, BL, ACC, 0, 0, 0);  \
  ACC = __builtin_amdgcn_mfma_f32_16x16x32_bf16(AH, BH, ACC, 0, 0, 0);

#define LOADB(P, S)                                   \
  {                                                   \
    const int kb = ((S) & 15) * 32;                   \
    P##h0 = *(const short8*)(bh + kb);                \
    P##h1 = *(const short8*)(bh + 8192 + kb);         \
    P##h2 = *(const short8*)(bh + 16384 + kb);        \
    P##h3 = *(const short8*)(bh + 24576 + kb);        \
    P##l0 = *(const short8*)(bl + kb);                \
    P##l1 = *(const short8*)(bl + 8192 + kb);         \
    P##l2 = *(const short8*)(bl + 16384 + kb);        \
    P##l3 = *(const short8*)(bl + 24576 + kb);        \
  }

#define LOADA(Aa, Ab, S)                              \
  {                                                   \
    const int ka = ((S) & 15) * 32;                   \
    Aa = *(const float4*)(xr + ka);                   \
    Ab = *(const float4*)(xr + ka + 4);               \
  }

#define SUBSTEP(Aa, Ab, P, SA, SB)                    \
  {                                                   \
    short8 ahi, alo;                                  \
    cvt8(Aa, Ab, ahi, alo);                           \
    MM3(acc0, ahi, alo, P##h0, P##l0);                \
    MM3(acc1, ahi, alo, P##h1, P##l1);                \
    MM3(acc2, ahi, alo, P##h2, P##l2);                \
    MM3(acc3, ahi, alo, P##h3, P##l3);                \
    LOADB(P, SB);                                     \
    LOADA(Aa, Ab, SA);                                \
  }

#define P2_BODY(GET_A)                                        \
  _Pragma("unroll")                                           \
  for (int j = 0; j < LCH; ++j) {                             \
    const float dtc = dtv[j], xv = xs[j];                     \
    sd += dtc;                                                \
    bpow *= beta;                                             \
    const float u = alpha * dtc * xv;                         \
    GET_A;                                                    \
    float4 Bq[4];                                             \
    _Pragma("unroll")                                         \
    for (int i = 0; i < 4; ++i) Bq[i] = ((const float4*)&Ps[j][DTR])[i]; \
    const float* Bf = (const float*)Bq;                       \
    float ar = 1.f;                                           \
    _Pragma("unroll")                                         \
    for (int n = 0; n < 16; ++n) {                            \
      NEXT_A(ar, n);                                          \
      v[n] = fmaf(beta, v[n], u * Bf[n]);                     \
      h[n] = fmaf(ar, h[n], v[n]);                            \
      cv[n] = fmaf(ar, cv[n], bpow);                          \
    }                                                         \
  }

#define P4_BODY(GET_A)                                        \
  _Pragma("unroll")                                           \
  for (int j = 0; j < LCH; ++j) {                             \
    const float dtc = dtv[j], xv = xs[j];                     \
    const float u = alpha * dtc * xv;                         \
    GET_A;                                                    \
    float4 Bq[8];                                             \
    _Pragma("unroll")                                         \
    for (int i = 0; i < 8; ++i) Bq[i] = ((const float4*)&Ps[j][DTR])[i]; \
    const float* Bf = (const float*)Bq;                       \
    float y0 = 0.f, y1 = 0.f, y2 = 0.f, y3 = 0.f;             \
    float ar = 1.f;                                           \
    _Pragma("unroll")                                         \
    for (int n = 0; n < 16; ++n) {                            \
      NEXT_A(ar, n);                                          \
      v[n] = fmaf(beta, v[n], u * Bf[n]);                     \
      h[n] = fmaf(ar, h[n], v[n]);                            \
      float hc = h[n] * Bf[16 + n];                           \
      if ((n & 3) == 0) y0 += hc;                             \
      else if ((n & 3) == 1) y1 += hc;                        \
      else if ((n & 3) == 2) y2 += hc;                        \
      else y3 += hc;                                          \
    }                                                         \
    op[(size_t)j * D_IN] = (y0 + y1) + (y2 + y3) + Dv * xv;   \
  }

__global__ __launch_bounds__(256, 2) void k_fused(
    const float* __restrict__ x, const float* __restrict__ A_log,
    const float* __restrict__ D_param, const float* __restrict__ W_xproj,
    const float* __restrict__ W_dt, const float* __restrict__ b_dt,
    const float* __restrict__ alpha_p, const float* __restrict__ beta_p,
    float* __restrict__ out, unsigned* __restrict__ bar, float* __restrict__ proj,
    float* __restrict__ sdt, f16* __restrict__ hh, f16* __restrict__ vh,
    f16* __restrict__ cvv, short* __restrict__ Whi, short* __restrict__ Wlo) {
  const int tid = threadIdx.x;
  const int bx = blockIdx.x;
  __shared__ float Ps[LCH][PDIM];  // 8 KB; persists P2 -> P4

  // ---- P0: W -> bf16 hi/lo (blocks 0..31) ----------------------------------
  if (bx < 32) {
    const int i = (bx * 256 + tid) * 4;
    float4 w = *(const float4*)(W_xproj + i);
    float f[4] = {w.x, w.y, w.z, w.w};
    unsigned short h4[4], l4[4];
#pragma unroll
    for (int j = 0; j < 4; ++j) {
      h4[j] = bf16_rne(f[j]);
      float r = f[j] - __uint_as_float((unsigned)h4[j] << 16);
      l4[j] = bf16_rne(r);
    }
    *(uint2*)(Whi + i) =
        make_uint2(h4[0] | ((unsigned)h4[1] << 16), h4[2] | ((unsigned)h4[3] << 16));
    *(uint2*)(Wlo + i) =
        make_uint2(l4[0] | ((unsigned)l4[1] << 16), l4[2] | ((unsigned)l4[3] << 16));
  }
  gbar(bar, 1 * NBLK);

  // ---- P1: proj = x @ W^T via MFMA bf16x3 (wave 0 of each block) -----------
  if (tid < 64) {
    const int row0 = bx * 16;
    const int m = tid & 15;
    const int ko = (tid >> 4) * 8;
    const float* xr = x + (size_t)(row0 + m) * D_IN + ko;
    const short* bh = Whi + (size_t)m * D_IN + ko;
    const short* bl = Wlo + (size_t)m * D_IN + ko;

    f32x4 acc0 = {0.f, 0.f, 0.f, 0.f}, acc1 = acc0, acc2 = acc0, acc3 = acc0;
    float4 A0a, A0b, A1a, A1b, A2a, A2b, A3a, A3b;
    short8 Xh0, Xh1, Xh2, Xh3, Xl0, Xl1, Xl2, Xl3;
    short8 Yh0, Yh1, Yh2, Yh3, Yl0, Yl1, Yl2, Yl3;
    LOADA(A0a, A0b, 0); LOADA(A1a, A1b, 1); LOADA(A2a, A2b, 2); LOADA(A3a, A3b, 3);
    LOADB(X, 0); LOADB(Y, 1);
#pragma unroll
    for (int it = 0; it < 4; ++it) {
      const int s = it * 4;
      SUBSTEP(A0a, A0b, X, s + 4, s + 2);
      SUBSTEP(A1a, A1b, Y, s + 5, s + 3);
      SUBSTEP(A2a, A2b, X, s + 6, s + 4);
      SUBSTEP(A3a, A3b, Y, s + 7, s + 5);
    }
    const int r0 = (tid >> 4) * 4;
#pragma unroll
    for (int r = 0; r < 4; ++r) {
      float* pr = proj + (size_t)(row0 + r0 + r) * PDIM + m;
      pr[0] = acc0[r]; pr[16] = acc1[r]; pr[32] = acc2[r]; pr[48] = acc3[r];
    }
  }
  gbar(bar, 2 * NBLK);

  // ---- shared coords / scalars ---------------------------------------------
  const float alpha = alpha_p[0];
  const float beta = 1.f / (1.f + __expf(-beta_p[0]));
  const int c = bx & (NCH - 1);
  const int b = bx >> 8;
  const int d = ((bx >> 7) & 1) * 256 + tid;
  const int t0 = c * LCH;
  const size_t base = ((size_t)(b * NCH + c) * D_IN + d) * D_ST;

  // ---- P2: stage chunk, dt once, zero-init scan, fp16 state out ------------
  {
    const float4* src = (const float4*)(proj + ((size_t)b * LSEQ + t0) * PDIM);
    float4* dst = (float4*)&Ps[0][0];
    dst[tid] = src[tid];
    dst[tid + 256] = src[tid + 256];
  }
  float xs[LCH];
  {
    const float* xp = x + ((size_t)b * LSEQ + t0) * D_IN + d;
#pragma unroll
    for (int j = 0; j < LCH; ++j) xs[j] = xp[(size_t)j * D_IN];
  }
  float A2[D_ST];
  const bool powA = loadA2(A_log, d, A2);
  __syncthreads();

  float dtv[LCH];
  {
    float4 w4[8];
    const float4* wp = (const float4*)(W_dt + (size_t)d * DTR);
#pragma unroll
    for (int i = 0; i < 8; ++i) w4[i] = wp[i];
    const float bb = b_dt[d];
#pragma unroll
    for (int j = 0; j < LCH; ++j) {
      const float4* pj = (const float4*)&Ps[j][0];
      float a0 = bb, a1 = 0.f, a2 = 0.f, a3 = 0.f;
#pragma unroll
      for (int k = 0; k < 8; ++k) {
        float4 p = pj[k];
        a0 = fmaf(p.x, w4[k].x, a0);
        a1 = fmaf(p.y, w4[k].y, a1);
        a2 = fmaf(p.z, w4[k].z, a2);
        a3 = fmaf(p.w, w4[k].w, a3);
      }
      float acc = (a0 + a1) + (a2 + a3);
      float e = fast_exp2(acc * LOG2E);
      dtv[j] = (acc > 20.f) ? acc : LN2 * fast_log2(1.f + e);
    }
  }

  {
    float h[16] = {}, v[16] = {}, cv[16] = {};
    float bpow = 1.f, sd = 0.f;
    if (powA) {
#define NEXT_A(ar, n) ar *= r
      P2_BODY(const float r = fast_exp2(dtc * A2[0]))
#undef NEXT_A
    } else {
#define NEXT_A(ar, n) ar = fast_exp2(dtc * A2[n])
      P2_BODY()
#undef NEXT_A
    }
    st16h(hh + base, h);
    st16h(vh + base, v);
    st16h(cvv + base, cv);
    sdt[(size_t)(b * NCH + c) * D_IN + d] = sd;
  }
  gbar(bar, 3 * NBLK);

  // ---- P3: serial fix over 128 chunks (blocks 0..63) -----------------------
  if (bx < 64) {
    const int g = bx * 256 + tid;  // 16384 = B*D*N
    const int b3 = g >> 13;
    const int dn = g & 8191;
    const float A2f = -__expf(A_log[dn]) * LOG2E;
    float bL = beta;
#pragma unroll
    for (int i = 0; i < 5; ++i) bL *= bL;  // beta^32 = beta^LCH

    const size_t cs = (size_t)D_IN * D_ST;
    const size_t fb = (size_t)b3 * NCH * cs + dn;
    const size_t sb = (size_t)b3 * NCH * D_IN + (dn >> 4);

    float hg[8], vg[8], cg[8], sg[8];
#pragma unroll
    for (int i = 0; i < 8; ++i) {
      hg[i] = (float)hh[fb + i * cs];
      vg[i] = (float)vh[fb + i * cs];
      cg[i] = (float)cvv[fb + i * cs];
      sg[i] = sdt[sb + i * D_IN];
    }
    float H = 0.f, V = 0.f;
    for (int c0 = 0; c0 < NCH; c0 += 8) {
      const int cp = (c0 + 8) & (NCH - 1);  // wraps; last prefetch unused
      float hn[8], vn[8], cn[8], sn[8];
#pragma unroll
      for (int i = 0; i < 8; ++i) {
        hn[i] = (float)hh[fb + (size_t)(cp + i) * cs];
        vn[i] = (float)vh[fb + (size_t)(cp + i) * cs];
        cn[i] = (float)cvv[fb + (size_t)(cp + i) * cs];
        sn[i] = sdt[sb + (size_t)(cp + i) * D_IN];
      }
#pragma unroll
      for (int i = 0; i < 8; ++i) {
        hh[fb + (size_t)(c0 + i) * cs] = (f16)H;
        vh[fb + (size_t)(c0 + i) * cs] = (f16)V;
        const float Pa = fast_exp2(sg[i] * A2f);
        const float Hn = fmaf(Pa, H, fmaf(cg[i], V, hg[i]));
        V = fmaf(bL, V, vg[i]);
        H = Hn;
      }
#pragma unroll
      for (int i = 0; i < 8; ++i) { hg[i] = hn[i]; vg[i] = vn[i]; cg[i] = cn[i]; sg[i] = sn[i]; }
    }
  }
  gbar(bar, 4 * NBLK);

  // ---- P4: final scan with fixed inits (dtv/xs/Ps retained), emit y --------
  {
    const float Dv = D_param[d];
    float h[16], v[16];
    ld16h(hh + base, h);
    ld16h(vh + base, v);
    float* op = out + ((size_t)b * LSEQ + t0) * D_IN + d;
    if (powA) {
#define NEXT_A(ar, n) ar *= r
      P4_BODY(const float r = fast_exp2(dtc * A2[0]))
#undef NEXT_A
    } else {
#define NEXT_A(ar, n) ar = fast_exp2(dtc * A2[n])
      P4_BODY()
#undef NEXT_A
    }
  }
}

extern "C" void kernel_launch(void* const* d_in, const int* in_sizes, int n_in,
                              void* d_out, int out_size, void* d_ws, size_t ws_size,
                              hipStream_t stream) {
  const float* x = (const float*)d_in[0];
  const float* A_log = (const float*)d_in[1];
  const float* D_param = (const float*)d_in[2];
  const float* W_xproj = (const float*)d_in[3];
  const float* W_dt = (const float*)d_in[4];
  const float* b_dt = (const float*)d_in[5];
  const float* alpha = (const float*)d_in[6];
  const float* beta_logit = (const float*)d_in[7];
  float* out = (float*)d_out;

  const size_t NST = (size_t)BSZ * NCH * D_IN * D_ST;  // 2097152
  unsigned* bar = (unsigned*)d_ws;                      // 256 B barrier region
  float* proj = (float*)((char*)d_ws + 256);            // 524288 floats
  float* sdt = proj + (size_t)BSZ * LSEQ * PDIM;        // 131072 floats
  f16* hh = (f16*)(sdt + (size_t)BSZ * NCH * D_IN);     // 2097152 halves
  f16* vh = hh + NST;
  f16* cvv = vh + NST;
  short* Whi = (short*)(cvv + NST);                     // 32768 shorts
  short* Wlo = Whi + (size_t)PDIM * D_IN;               // total ~15.5 MB

  hipMemsetAsync(d_ws, 0, 256, stream);  // zero barrier counter (captured node)
  k_fused<<<dim3(NBLK), dim3(256), 0, stream>>>(x, A_log, D_param, W_xproj, W_dt, b_dt,
                                                alpha, beta_logit, out, bar, proj, sdt,
                                                hh, vh, cvv, Whi, Wlo);
}

// Round 14
// 176.192 us; speedup vs baseline: 2.5809x; 2.5809x over previous
//
#include <hip/hip_runtime.h>

// MomentumSSM B=2, L=4096, D=512, N=16, R=32, P=64 — chunk-parallel scan, NCH=256.
// R14 = R12 (proven 172 us) minus the dth intermediate (scan2 recomputes dt
// from the LDS proj chunk with the fast softplus — cheap now, and bit-identical
// to scan1's fp32 dt), plus k_fix group-16 lookahead (16 latency segments
// instead of 32). R13's fused-kernel attempt showed manual grid barriers cost
// ~80 us each (512 blocks on one atomic line) — fusion abandoned.
//
// v_t = beta*v + alpha*inp ; h_t = a_t*h + v ; a_t = exp(dt*A_n)
// chunk map: h_end = Pa*H0 + cv*V0 + hhat ; v_end = beta^LCH*V0 + vhat

#define D_IN 512
#define D_ST 16
#define DTR  32
#define BSZ  2
#define LSEQ 4096
#define PDIM 64
#define NCH  256
#define LCH  (LSEQ / NCH)  // 16
#define LOG2E 1.44269504f
#define LN2   0.69314718f

typedef __attribute__((ext_vector_type(8))) short short8;
typedef __attribute__((ext_vector_type(4))) float f32x4;
typedef _Float16 f16;
typedef __attribute__((ext_vector_type(8))) _Float16 f16x8;

__device__ inline float fast_exp2(float x) { return __builtin_amdgcn_exp2f(x); }
__device__ inline float fast_log2(float x) { return __builtin_amdgcn_logf(x); }

__device__ inline unsigned short bf16_rne(float f) {
  unsigned b = __float_as_uint(f);
  return (unsigned short)((b + 0x7fffu + ((b >> 16) & 1u)) >> 16);
}

__device__ inline void cvt8(const float4 u, const float4 v, short8& hi, short8& lo) {
  float f[8] = {u.x, u.y, u.z, u.w, v.x, v.y, v.z, v.w};
#pragma unroll
  for (int i = 0; i < 8; ++i) {
    unsigned short h = bf16_rne(f[i]);
    hi[i] = (short)h;
    float r = f[i] - __uint_as_float((unsigned)h << 16);
    lo[i] = (short)bf16_rne(r);
  }
}

__device__ inline void st16h(f16* p, const float* s) {
  f16 t[16];
#pragma unroll
  for (int i = 0; i < 16; ++i) t[i] = (f16)s[i];
  *(f16x8*)p = *(f16x8*)&t[0];
  *(f16x8*)(p + 8) = *(f16x8*)&t[8];
}
__device__ inline void ld16h(const f16* p, float* d) {
  f16x8 a = *(const f16x8*)p;
  f16x8 b = *(const f16x8*)(p + 8);
#pragma unroll
  for (int i = 0; i < 8; ++i) { d[i] = (float)a[i]; d[8 + i] = (float)b[i]; }
}

// load A2 row; detect arithmetic-progression structure (A2[n]=(n+1)*A2[0])
__device__ inline bool loadA2(const float* A_log, int d, float* A2) {
  const float4* ap = (const float4*)(A_log + (size_t)d * D_ST);
#pragma unroll
  for (int i = 0; i < 4; ++i) {
    float4 a4 = ap[i];
    A2[4 * i + 0] = -__expf(a4.x) * LOG2E;
    A2[4 * i + 1] = -__expf(a4.y) * LOG2E;
    A2[4 * i + 2] = -__expf(a4.z) * LOG2E;
    A2[4 * i + 3] = -__expf(a4.w) * LOG2E;
  }
  bool pw = true;
#pragma unroll
  for (int n = 1; n < 16; ++n) {
    float ref = (float)(n + 1) * A2[0];
    pw = pw && (fabsf(A2[n] - ref) <= 2e-5f * fabsf(ref));
  }
  return pw;
}

// dt = softplus(proj_chunk[:, :32] @ wdt + bb) from LDS, fast path
#define DT_FROM_LDS(dtv, Ps)                                  \
  {                                                           \
    float4 w4[8];                                             \
    const float4* wp = (const float4*)(W_dt + (size_t)d * DTR); \
    _Pragma("unroll")                                         \
    for (int i = 0; i < 8; ++i) w4[i] = wp[i];                \
    const float bb = b_dt[d];                                 \
    _Pragma("unroll")                                         \
    for (int j = 0; j < LCH; ++j) {                           \
      const float4* pj = (const float4*)&Ps[j][0];            \
      float a0 = bb, a1 = 0.f, a2 = 0.f, a3 = 0.f;            \
      _Pragma("unroll")                                       \
      for (int k = 0; k < 8; ++k) {                           \
        float4 p = pj[k];                                     \
        a0 = fmaf(p.x, w4[k].x, a0);                          \
        a1 = fmaf(p.y, w4[k].y, a1);                          \
        a2 = fmaf(p.z, w4[k].z, a2);                          \
        a3 = fmaf(p.w, w4[k].w, a3);                          \
      }                                                       \
      float acc = (a0 + a1) + (a2 + a3);                      \
      float e = fast_exp2(acc * LOG2E);                       \
      dtv[j] = (acc > 20.f) ? acc : LN2 * fast_log2(1.f + e); \
    }                                                         \
  }

// ---------------- W -> bf16 hi/lo split --------------------------------------
__global__ __launch_bounds__(256) void k_wprep(const float* __restrict__ W,
                                               short* __restrict__ Whi,
                                               short* __restrict__ Wlo) {
  const int i = (blockIdx.x * 256 + threadIdx.x) * 4;
  float4 w = *(const float4*)(W + i);
  float f[4] = {w.x, w.y, w.z, w.w};
  unsigned short h[4], lo[4];
#pragma unroll
  for (int j = 0; j < 4; ++j) {
    h[j] = bf16_rne(f[j]);
    float r = f[j] - __uint_as_float((unsigned)h[j] << 16);
    lo[j] = bf16_rne(r);
  }
  *(uint2*)(Whi + i) = make_uint2(h[0] | ((unsigned)h[1] << 16), h[2] | ((unsigned)h[3] << 16));
  *(uint2*)(Wlo + i) = make_uint2(lo[0] | ((unsigned)lo[1] << 16), lo[2] | ((unsigned)lo[3] << 16));
}

// ---------------- proj = x @ W^T via MFMA bf16x3 (R5-proven) -----------------
#define MM3(ACC, AH, AL, BH, BL)                                        \
  ACC = __builtin_amdgcn_mfma_f32_16x16x32_bf16(AL, BH, ACC, 0, 0, 0);  \
  ACC = __builtin_amdgcn_mfma_f32_16x16x32_bf16(AH, BL, ACC, 0, 0, 0);  \
  ACC = __builtin_amdgcn_mfma_f32_16x16x32_bf16(AH, BH, ACC, 0, 0, 0);

#define LOADB(P, S)                                   \
  {                                                   \
    const int kb = ((S) & 15) * 32;                   \
    P##h0 = *(const short8*)(bh + kb);                \
    P##h1 = *(const short8*)(bh + 8192 + kb);         \
    P##h2 = *(const short8*)(bh + 16384 + kb);        \
    P##h3 = *(const short8*)(bh + 24576 + kb);        \
    P##l0 = *(const short8*)(bl + kb);                \
    P##l1 = *(const short8*)(bl + 8192 + kb);         \
    P##l2 = *(const short8*)(bl + 16384 + kb);        \
    P##l3 = *(const short8*)(bl + 24576 + kb);        \
  }

#define LOADA(Aa, Ab, S)                              \
  {                                                   \
    const int ka = ((S) & 15) * 32;                   \
    Aa = *(const float4*)(xr + ka);                   \
    Ab = *(const float4*)(xr + ka + 4);               \
  }

#define SUBSTEP(Aa, Ab, P, SA, SB)                    \
  {                                                   \
    short8 ahi, alo;                                  \
    cvt8(Aa, Ab, ahi, alo);                           \
    MM3(acc0, ahi, alo, P##h0, P##l0);                \
    MM3(acc1, ahi, alo, P##h1, P##l1);                \
    MM3(acc2, ahi, alo, P##h2, P##l2);                \
    MM3(acc3, ahi, alo, P##h3, P##l3);                \
    LOADB(P, SB);                                     \
    LOADA(Aa, Ab, SA);                                \
  }

__global__ __launch_bounds__(64) void k_proj(const float* __restrict__ x,
                                             const short* __restrict__ Whi,
                                             const short* __restrict__ Wlo,
                                             float* __restrict__ proj) {
  const int row0 = blockIdx.x * 16;
  const int l = threadIdx.x;
  const int m = l & 15;
  const int ko = (l >> 4) * 8;
  const float* xr = x + (size_t)(row0 + m) * D_IN + ko;
  const short* bh = Whi + (size_t)m * D_IN + ko;
  const short* bl = Wlo + (size_t)m * D_IN + ko;

  f32x4 acc0 = {0.f, 0.f, 0.f, 0.f}, acc1 = acc0, acc2 = acc0, acc3 = acc0;
  float4 A0a, A0b, A1a, A1b, A2a, A2b, A3a, A3b;
  short8 Xh0, Xh1, Xh2, Xh3, Xl0, Xl1, Xl2, Xl3;
  short8 Yh0, Yh1, Yh2, Yh3, Yl0, Yl1, Yl2, Yl3;
  LOADA(A0a, A0b, 0); LOADA(A1a, A1b, 1); LOADA(A2a, A2b, 2); LOADA(A3a, A3b, 3);
  LOADB(X, 0); LOADB(Y, 1);

#pragma unroll
  for (int it = 0; it < 4; ++it) {
    const int s = it * 4;
    SUBSTEP(A0a, A0b, X, s + 4, s + 2);
    SUBSTEP(A1a, A1b, Y, s + 5, s + 3);
    SUBSTEP(A2a, A2b, X, s + 6, s + 4);
    SUBSTEP(A3a, A3b, Y, s + 7, s + 5);
  }

  const int r0 = (l >> 4) * 4;
#pragma unroll
  for (int r = 0; r < 4; ++r) {
    float* pr = proj + (size_t)(row0 + r0 + r) * PDIM + m;
    pr[0] = acc0[r]; pr[16] = acc1[r]; pr[32] = acc2[r]; pr[48] = acc3[r];
  }
}

// ---------------- pass 1: dt from LDS, zero-init scan, fp16 state out --------
#define S1_BODY(GET_A)                                        \
  _Pragma("unroll")                                           \
  for (int j = 0; j < LCH; ++j) {                             \
    const float dtc = dtv[j], xv = xs[j];                     \
    sd += dtc;                                                \
    bpow *= beta;                                             \
    const float u = alpha * dtc * xv;                         \
    GET_A;                                                    \
    float4 Bq[4];                                             \
    _Pragma("unroll")                                         \
    for (int i = 0; i < 4; ++i) Bq[i] = ((const float4*)&Ps[j][DTR])[i]; \
    const float* Bf = (const float*)Bq;                       \
    float ar = 1.f;                                           \
    _Pragma("unroll")                                         \
    for (int n = 0; n < 16; ++n) {                            \
      NEXT_A(ar, n);                                          \
      v[n] = fmaf(beta, v[n], u * Bf[n]);                     \
      h[n] = fmaf(ar, h[n], v[n]);                            \
      cv[n] = fmaf(ar, cv[n], bpow);                          \
    }                                                         \
  }

__global__ __launch_bounds__(256) void k_scan1(const float* __restrict__ x,
                                               const float* __restrict__ proj,
                                               const float* __restrict__ A_log,
                                               const float* __restrict__ W_dt,
                                               const float* __restrict__ b_dt,
                                               const float* __restrict__ alpha_p,
                                               const float* __restrict__ beta_p,
                                               f16* __restrict__ hh,
                                               f16* __restrict__ vh,
                                               f16* __restrict__ cvv,
                                               float* __restrict__ sdt) {
  __shared__ float Ps[LCH][PDIM];
  const int c = blockIdx.x, b = blockIdx.z;
  const int d = blockIdx.y * 256 + threadIdx.x;
  const int t0 = c * LCH;
  {
    const float4* src = (const float4*)(proj + ((size_t)b * LSEQ + t0) * PDIM);
    ((float4*)&Ps[0][0])[threadIdx.x] = src[threadIdx.x];
  }
  float xs[LCH];
  {
    const float* xp = x + ((size_t)b * LSEQ + t0) * D_IN + d;
#pragma unroll
    for (int j = 0; j < LCH; ++j) xs[j] = xp[(size_t)j * D_IN];
  }
  const float alpha = alpha_p[0];
  const float beta = 1.f / (1.f + __expf(-beta_p[0]));
  float A2[D_ST];
  const bool powA = loadA2(A_log, d, A2);
  __syncthreads();

  float dtv[LCH];
  DT_FROM_LDS(dtv, Ps);

  float h[16] = {}, v[16] = {}, cv[16] = {};
  float bpow = 1.f, sd = 0.f;
  if (powA) {
#define NEXT_A(ar, n) ar *= r
    S1_BODY(const float r = fast_exp2(dtc * A2[0]))
#undef NEXT_A
  } else {
#define NEXT_A(ar, n) ar = fast_exp2(dtc * A2[n])
    S1_BODY()
#undef NEXT_A
  }

  const size_t base = ((size_t)(b * NCH + c) * D_IN + d) * D_ST;
  st16h(hh + base, h);
  st16h(vh + base, v);
  st16h(cvv + base, cv);
  sdt[(size_t)(b * NCH + c) * D_IN + d] = sd;
}

// ---------------- fixup: scan over 256 chunks; group-16 lookahead ------------
__global__ __launch_bounds__(64) void k_fix(f16* __restrict__ hh,
                                            f16* __restrict__ vh,
                                            const f16* __restrict__ cvv,
                                            const float* __restrict__ sdt,
                                            const float* __restrict__ A_log,
                                            const float* __restrict__ beta_p) {
  const int g = blockIdx.x * 64 + threadIdx.x;  // 16384 = B * D * N
  const int b = g >> 13;
  const int dn = g & 8191;
  const float beta = 1.f / (1.f + __expf(-beta_p[0]));
  const float A2 = -__expf(A_log[dn]) * LOG2E;
  float bL = beta;
#pragma unroll
  for (int i = 0; i < 4; ++i) bL *= bL;  // beta^16 = beta^LCH

  const size_t cs = (size_t)D_IN * D_ST;
  const size_t base = (size_t)b * NCH * cs + dn;
  const size_t sbase = (size_t)b * NCH * D_IN + (dn >> 4);

  float hg[16], vg[16], cg[16], sg[16];
#pragma unroll
  for (int i = 0; i < 16; ++i) {
    hg[i] = (float)hh[base + i * cs];
    vg[i] = (float)vh[base + i * cs];
    cg[i] = (float)cvv[base + i * cs];
    sg[i] = sdt[sbase + i * D_IN];
  }
  float H = 0.f, V = 0.f;
  for (int c0 = 0; c0 < NCH; c0 += 16) {
    const int cp = (c0 + 16) & (NCH - 1);  // wraps; last prefetch unused
    float hn[16], vn[16], cn[16], sn[16];
#pragma unroll
    for (int i = 0; i < 16; ++i) {
      hn[i] = (float)hh[base + (size_t)(cp + i) * cs];
      vn[i] = (float)vh[base + (size_t)(cp + i) * cs];
      cn[i] = (float)cvv[base + (size_t)(cp + i) * cs];
      sn[i] = sdt[sbase + (size_t)(cp + i) * D_IN];
    }
#pragma unroll
    for (int i = 0; i < 16; ++i) {
      hh[base + (size_t)(c0 + i) * cs] = (f16)H;
      vh[base + (size_t)(c0 + i) * cs] = (f16)V;
      const float Pa = fast_exp2(sg[i] * A2);
      const float Hn = fmaf(Pa, H, fmaf(cg[i], V, hg[i]));
      V = fmaf(bL, V, vg[i]);
      H = Hn;
    }
#pragma unroll
    for (int i = 0; i < 16; ++i) { hg[i] = hn[i]; vg[i] = vn[i]; cg[i] = cn[i]; sg[i] = sn[i]; }
  }
}

// ---------------- pass 2: dt from LDS, correct-init scan, emit y -------------
#define S2_BODY(GET_A)                                        \
  _Pragma("unroll")                                           \
  for (int j = 0; j < LCH; ++j) {                             \
    const float dtc = dtv[j], xv = xs[j];                     \
    const float u = alpha * dtc * xv;                         \
    GET_A;                                                    \
    float4 Bq[8];                                             \
    _Pragma("unroll")                                         \
    for (int i = 0; i < 8; ++i) Bq[i] = ((const float4*)&Ps[j][DTR])[i]; \
    const float* Bf = (const float*)Bq;                       \
    float y0 = 0.f, y1 = 0.f, y2 = 0.f, y3 = 0.f;             \
    float ar = 1.f;                                           \
    _Pragma("unroll")                                         \
    for (int n = 0; n < 16; ++n) {                            \
      NEXT_A(ar, n);                                          \
      v[n] = fmaf(beta, v[n], u * Bf[n]);                     \
      h[n] = fmaf(ar, h[n], v[n]);                            \
      float hc = h[n] * Bf[16 + n];                           \
      if ((n & 3) == 0) y0 += hc;                             \
      else if ((n & 3) == 1) y1 += hc;                        \
      else if ((n & 3) == 2) y2 += hc;                        \
      else y3 += hc;                                          \
    }                                                         \
    op[(size_t)j * D_IN] = (y0 + y1) + (y2 + y3) + Dv * xv;   \
  }

__global__ __launch_bounds__(256) void k_scan2(const float* __restrict__ x,
                                               const float* __restrict__ proj,
                                               const float* __restrict__ A_log,
                                               const float* __restrict__ D_param,
                                               const float* __restrict__ W_dt,
                                               const float* __restrict__ b_dt,
                                               const float* __restrict__ alpha_p,
                                               const float* __restrict__ beta_p,
                                               const f16* __restrict__ hh,
                                               const f16* __restrict__ vh,
                                               float* __restrict__ out) {
  __shared__ float Ps[LCH][PDIM];
  const int c = blockIdx.x, b = blockIdx.z;
  const int d = blockIdx.y * 256 + threadIdx.x;
  const int t0 = c * LCH;
  {
    const float4* src = (const float4*)(proj + ((size_t)b * LSEQ + t0) * PDIM);
    ((float4*)&Ps[0][0])[threadIdx.x] = src[threadIdx.x];
  }
  float xs[LCH];
  {
    const float* xp = x + ((size_t)b * LSEQ + t0) * D_IN + d;
#pragma unroll
    for (int j = 0; j < LCH; ++j) xs[j] = xp[(size_t)j * D_IN];
  }
  const float alpha = alpha_p[0];
  const float beta = 1.f / (1.f + __expf(-beta_p[0]));
  const float Dv = D_param[d];
  float A2[D_ST];
  const bool powA = loadA2(A_log, d, A2);
  const size_t ibase = ((size_t)(b * NCH + c) * D_IN + d) * D_ST;
  float h[16], v[16];
  ld16h(hh + ibase, h);
  ld16h(vh + ibase, v);
  __syncthreads();

  float dtv[LCH];
  DT_FROM_LDS(dtv, Ps);

  float* op = out + ((size_t)b * LSEQ + t0) * D_IN + d;
  if (powA) {
#define NEXT_A(ar, n) ar *= r
    S2_BODY(const float r = fast_exp2(dtc * A2[0]))
#undef NEXT_A
  } else {
#define NEXT_A(ar, n) ar = fast_exp2(dtc * A2[n])
    S2_BODY()
#undef NEXT_A
  }
}

extern "C" void kernel_launch(void* const* d_in, const int* in_sizes, int n_in,
                              void* d_out, int out_size, void* d_ws, size_t ws_size,
                              hipStream_t stream) {
  const float* x = (const float*)d_in[0];
  const float* A_log = (const float*)d_in[1];
  const float* D_param = (const float*)d_in[2];
  const float* W_xproj = (const float*)d_in[3];
  const float* W_dt = (const float*)d_in[4];
  const float* b_dt = (const float*)d_in[5];
  const float* alpha = (const float*)d_in[6];
  const float* beta_logit = (const float*)d_in[7];
  float* out = (float*)d_out;

  const size_t NST = (size_t)BSZ * NCH * D_IN * D_ST;  // 4194304
  float* ws = (float*)d_ws;
  float* proj = ws;                                  // 524288 floats
  float* sdt = proj + (size_t)BSZ * LSEQ * PDIM;     // 262144 floats
  f16* hh = (f16*)(sdt + (size_t)BSZ * NCH * D_IN);  // 4194304 halves
  f16* vh = hh + NST;
  f16* cvv = vh + NST;
  short* Whi = (short*)(cvv + NST);                  // 32768 shorts
  short* Wlo = Whi + (size_t)PDIM * D_IN;            // total ~28.5 MB

  k_wprep<<<dim3(PDIM * D_IN / 1024), dim3(256), 0, stream>>>(W_xproj, Whi, Wlo);
  k_proj<<<dim3(BSZ * LSEQ / 16), dim3(64), 0, stream>>>(x, Whi, Wlo, proj);
  k_scan1<<<dim3(NCH, D_IN / 256, BSZ), dim3(256), 0, stream>>>(
      x, proj, A_log, W_dt, b_dt, alpha, beta_logit, hh, vh, cvv, sdt);
  k_fix<<<dim3(BSZ * D_IN * D_ST / 64), dim3(64), 0, stream>>>(hh, vh, cvv, sdt, A_log,
                                                               beta_logit);
  k_scan2<<<dim3(NCH, D_IN / 256, BSZ), dim3(256), 0, stream>>>(
      x, proj, A_log, D_param, W_dt, b_dt, alpha, beta_logit, hh, vh, out);
}

// Round 15
// 171.604 us; speedup vs baseline: 2.6499x; 1.0267x over previous
//
#include <hip/hip_runtime.h>

// MomentumSSM B=2, L=4096, D=512, N=16, R=32, P=64 — chunk-parallel scan, NCH=256.
// FINAL (R12 config, proven best 172.2 us): 5 dispatches
//   k_wprep -> k_proj (MFMA bf16x3) -> k_scan1 -> k_fix -> k_scan2
// - fp16 inter-kernel state (hh/vh/cv/dt), fp32 arithmetic
// - dt computed once in scan1 (fast softplus via exp2/log2 builtins)
// - a_n = exp2(dt*A2[n]) as running product r^(n+1) when A2 is an arithmetic
//   progression (runtime-verified; general-exp fallback), register-neutral
// - NCH=256 -> 1024 scan blocks (~4/CU)
// Disproven paths: coop launch (fails), manual grid barrier (~80us/sync, R13),
// dynamic-index prefetch arrays (scratch spill, R3/R11), dt recompute in scan2
// (neutral-negative, R14).
//
// v_t = beta*v + alpha*inp ; h_t = a_t*h + v ; a_t = exp(dt*A_n)
// chunk map: h_end = Pa*H0 + cv*V0 + hhat ; v_end = beta^LCH*V0 + vhat

#define D_IN 512
#define D_ST 16
#define DTR  32
#define BSZ  2
#define LSEQ 4096
#define PDIM 64
#define NCH  256
#define LCH  (LSEQ / NCH)  // 16
#define LOG2E 1.44269504f
#define LN2   0.69314718f

typedef __attribute__((ext_vector_type(8))) short short8;
typedef __attribute__((ext_vector_type(4))) float f32x4;
typedef _Float16 f16;
typedef __attribute__((ext_vector_type(8))) _Float16 f16x8;

__device__ inline float fast_exp2(float x) { return __builtin_amdgcn_exp2f(x); }
__device__ inline float fast_log2(float x) { return __builtin_amdgcn_logf(x); }

__device__ inline unsigned short bf16_rne(float f) {
  unsigned b = __float_as_uint(f);
  return (unsigned short)((b + 0x7fffu + ((b >> 16) & 1u)) >> 16);
}

__device__ inline void cvt8(const float4 u, const float4 v, short8& hi, short8& lo) {
  float f[8] = {u.x, u.y, u.z, u.w, v.x, v.y, v.z, v.w};
#pragma unroll
  for (int i = 0; i < 8; ++i) {
    unsigned short h = bf16_rne(f[i]);
    hi[i] = (short)h;
    float r = f[i] - __uint_as_float((unsigned)h << 16);
    lo[i] = (short)bf16_rne(r);
  }
}

__device__ inline void st16h(f16* p, const float* s) {
  f16 t[16];
#pragma unroll
  for (int i = 0; i < 16; ++i) t[i] = (f16)s[i];
  *(f16x8*)p = *(f16x8*)&t[0];
  *(f16x8*)(p + 8) = *(f16x8*)&t[8];
}
__device__ inline void ld16h(const f16* p, float* d) {
  f16x8 a = *(const f16x8*)p;
  f16x8 b = *(const f16x8*)(p + 8);
#pragma unroll
  for (int i = 0; i < 8; ++i) { d[i] = (float)a[i]; d[8 + i] = (float)b[i]; }
}

// load A2 row; detect arithmetic-progression structure (A2[n]=(n+1)*A2[0])
__device__ inline bool loadA2(const float* A_log, int d, float* A2) {
  const float4* ap = (const float4*)(A_log + (size_t)d * D_ST);
#pragma unroll
  for (int i = 0; i < 4; ++i) {
    float4 a4 = ap[i];
    A2[4 * i + 0] = -__expf(a4.x) * LOG2E;
    A2[4 * i + 1] = -__expf(a4.y) * LOG2E;
    A2[4 * i + 2] = -__expf(a4.z) * LOG2E;
    A2[4 * i + 3] = -__expf(a4.w) * LOG2E;
  }
  bool pw = true;
#pragma unroll
  for (int n = 1; n < 16; ++n) {
    float ref = (float)(n + 1) * A2[0];
    pw = pw && (fabsf(A2[n] - ref) <= 2e-5f * fabsf(ref));
  }
  return pw;
}

// ---------------- W -> bf16 hi/lo split --------------------------------------
__global__ __launch_bounds__(256) void k_wprep(const float* __restrict__ W,
                                               short* __restrict__ Whi,
                                               short* __restrict__ Wlo) {
  const int i = (blockIdx.x * 256 + threadIdx.x) * 4;
  float4 w = *(const float4*)(W + i);
  float f[4] = {w.x, w.y, w.z, w.w};
  unsigned short h[4], lo[4];
#pragma unroll
  for (int j = 0; j < 4; ++j) {
    h[j] = bf16_rne(f[j]);
    float r = f[j] - __uint_as_float((unsigned)h[j] << 16);
    lo[j] = bf16_rne(r);
  }
  *(uint2*)(Whi + i) = make_uint2(h[0] | ((unsigned)h[1] << 16), h[2] | ((unsigned)h[3] << 16));
  *(uint2*)(Wlo + i) = make_uint2(lo[0] | ((unsigned)lo[1] << 16), lo[2] | ((unsigned)lo[3] << 16));
}

// ---------------- proj = x @ W^T via MFMA bf16x3 (R5-proven) -----------------
#define MM3(ACC, AH, AL, BH, BL)                                        \
  ACC = __builtin_amdgcn_mfma_f32_16x16x32_bf16(AL, BH, ACC, 0, 0, 0);  \
  ACC = __builtin_amdgcn_mfma_f32_16x16x32_bf16(AH, BL, ACC, 0, 0, 0);  \
  ACC = __builtin_amdgcn_mfma_f32_16x16x32_bf16(AH, BH, ACC, 0, 0, 0);

#define LOADB(P, S)                                   \
  {                                                   \
    const int kb = ((S) & 15) * 32;                   \
    P##h0 = *(const short8*)(bh + kb);                \
    P##h1 = *(const short8*)(bh + 8192 + kb);         \
    P##h2 = *(const short8*)(bh + 16384 + kb);        \
    P##h3 = *(const short8*)(bh + 24576 + kb);        \
    P##l0 = *(const short8*)(bl + kb);                \
    P##l1 = *(const short8*)(bl + 8192 + kb);         \
    P##l2 = *(const short8*)(bl + 16384 + kb);        \
    P##l3 = *(const short8*)(bl + 24576 + kb);        \
  }

#define LOADA(Aa, Ab, S)                              \
  {                                                   \
    const int ka = ((S) & 15) * 32;                   \
    Aa = *(const float4*)(xr + ka);                   \
    Ab = *(const float4*)(xr + ka + 4);               \
  }

#define SUBSTEP(Aa, Ab, P, SA, SB)                    \
  {                                                   \
    short8 ahi, alo;                                  \
    cvt8(Aa, Ab, ahi, alo);                           \
    MM3(acc0, ahi, alo, P##h0, P##l0);                \
    MM3(acc1, ahi, alo, P##h1, P##l1);                \
    MM3(acc2, ahi, alo, P##h2, P##l2);                \
    MM3(acc3, ahi, alo, P##h3, P##l3);                \
    LOADB(P, SB);                                     \
    LOADA(Aa, Ab, SA);                                \
  }

__global__ __launch_bounds__(64) void k_proj(const float* __restrict__ x,
                                             const short* __restrict__ Whi,
                                             const short* __restrict__ Wlo,
                                             float* __restrict__ proj) {
  const int row0 = blockIdx.x * 16;
  const int l = threadIdx.x;
  const int m = l & 15;
  const int ko = (l >> 4) * 8;
  const float* xr = x + (size_t)(row0 + m) * D_IN + ko;
  const short* bh = Whi + (size_t)m * D_IN + ko;
  const short* bl = Wlo + (size_t)m * D_IN + ko;

  f32x4 acc0 = {0.f, 0.f, 0.f, 0.f}, acc1 = acc0, acc2 = acc0, acc3 = acc0;
  float4 A0a, A0b, A1a, A1b, A2a, A2b, A3a, A3b;
  short8 Xh0, Xh1, Xh2, Xh3, Xl0, Xl1, Xl2, Xl3;
  short8 Yh0, Yh1, Yh2, Yh3, Yl0, Yl1, Yl2, Yl3;
  LOADA(A0a, A0b, 0); LOADA(A1a, A1b, 1); LOADA(A2a, A2b, 2); LOADA(A3a, A3b, 3);
  LOADB(X, 0); LOADB(Y, 1);

#pragma unroll
  for (int it = 0; it < 4; ++it) {
    const int s = it * 4;
    SUBSTEP(A0a, A0b, X, s + 4, s + 2);
    SUBSTEP(A1a, A1b, Y, s + 5, s + 3);
    SUBSTEP(A2a, A2b, X, s + 6, s + 4);
    SUBSTEP(A3a, A3b, Y, s + 7, s + 5);
  }

  const int r0 = (l >> 4) * 4;
#pragma unroll
  for (int r = 0; r < 4; ++r) {
    float* pr = proj + (size_t)(row0 + r0 + r) * PDIM + m;
    pr[0] = acc0[r]; pr[16] = acc1[r]; pr[32] = acc2[r]; pr[48] = acc3[r];
  }
}

// ---------------- pass 1: dt once, zero-init scan, fp16 state out ------------
#define S1_BODY(GET_A)                                        \
  _Pragma("unroll")                                           \
  for (int j = 0; j < LCH; ++j) {                             \
    const float dtc = dtv[j], xv = xs[j];                     \
    sd += dtc;                                                \
    bpow *= beta;                                             \
    const float u = alpha * dtc * xv;                         \
    GET_A;                                                    \
    float4 Bq[4];                                             \
    _Pragma("unroll")                                         \
    for (int i = 0; i < 4; ++i) Bq[i] = ((const float4*)&Ps[j][DTR])[i]; \
    const float* Bf = (const float*)Bq;                       \
    float ar = 1.f;                                           \
    _Pragma("unroll")                                         \
    for (int n = 0; n < 16; ++n) {                            \
      NEXT_A(ar, n);                                          \
      v[n] = fmaf(beta, v[n], u * Bf[n]);                     \
      h[n] = fmaf(ar, h[n], v[n]);                            \
      cv[n] = fmaf(ar, cv[n], bpow);                          \
    }                                                         \
  }

__global__ __launch_bounds__(256) void k_scan1(const float* __restrict__ x,
                                               const float* __restrict__ proj,
                                               const float* __restrict__ A_log,
                                               const float* __restrict__ W_dt,
                                               const float* __restrict__ b_dt,
                                               const float* __restrict__ alpha_p,
                                               const float* __restrict__ beta_p,
                                               f16* __restrict__ hh,
                                               f16* __restrict__ vh,
                                               f16* __restrict__ cvv,
                                               float* __restrict__ sdt,
                                               f16* __restrict__ dth) {
  __shared__ float Ps[LCH][PDIM];
  const int c = blockIdx.x, b = blockIdx.z;
  const int d = blockIdx.y * 256 + threadIdx.x;
  const int t0 = c * LCH;
  {
    const float4* src = (const float4*)(proj + ((size_t)b * LSEQ + t0) * PDIM);
    ((float4*)&Ps[0][0])[threadIdx.x] = src[threadIdx.x];
  }
  float xs[LCH];
  {
    const float* xp = x + ((size_t)b * LSEQ + t0) * D_IN + d;
#pragma unroll
    for (int j = 0; j < LCH; ++j) xs[j] = xp[(size_t)j * D_IN];
  }
  const float alpha = alpha_p[0];
  const float beta = 1.f / (1.f + __expf(-beta_p[0]));
  float A2[D_ST];
  const bool powA = loadA2(A_log, d, A2);
  __syncthreads();

  float dtv[LCH];
  {
    float4 w4[8];
    const float4* wp = (const float4*)(W_dt + (size_t)d * DTR);
#pragma unroll
    for (int i = 0; i < 8; ++i) w4[i] = wp[i];
    const float bb = b_dt[d];
#pragma unroll
    for (int j = 0; j < LCH; ++j) {
      const float4* pj = (const float4*)&Ps[j][0];
      float a0 = bb, a1 = 0.f, a2 = 0.f, a3 = 0.f;
#pragma unroll
      for (int k = 0; k < 8; ++k) {
        float4 p = pj[k];
        a0 = fmaf(p.x, w4[k].x, a0);
        a1 = fmaf(p.y, w4[k].y, a1);
        a2 = fmaf(p.z, w4[k].z, a2);
        a3 = fmaf(p.w, w4[k].w, a3);
      }
      float acc = (a0 + a1) + (a2 + a3);
      float e = fast_exp2(acc * LOG2E);
      dtv[j] = (acc > 20.f) ? acc : LN2 * fast_log2(1.f + e);
    }
  }
  {
    f16* dp = dth + ((size_t)b * LSEQ + t0) * D_IN + d;
#pragma unroll
    for (int j = 0; j < LCH; ++j) dp[(size_t)j * D_IN] = (f16)dtv[j];
  }

  float h[16] = {}, v[16] = {}, cv[16] = {};
  float bpow = 1.f, sd = 0.f;
  if (powA) {
#define NEXT_A(ar, n) ar *= r
    S1_BODY(const float r = fast_exp2(dtc * A2[0]))
#undef NEXT_A
  } else {
#define NEXT_A(ar, n) ar = fast_exp2(dtc * A2[n])
    S1_BODY()
#undef NEXT_A
  }

  const size_t base = ((size_t)(b * NCH + c) * D_IN + d) * D_ST;
  st16h(hh + base, h);
  st16h(vh + base, v);
  st16h(cvv + base, cv);
  sdt[(size_t)(b * NCH + c) * D_IN + d] = sd;
}

// ---------------- fixup: scan over 256 chunks; group-8 lookahead -------------
__global__ __launch_bounds__(64) void k_fix(f16* __restrict__ hh,
                                            f16* __restrict__ vh,
                                            const f16* __restrict__ cvv,
                                            const float* __restrict__ sdt,
                                            const float* __restrict__ A_log,
                                            const float* __restrict__ beta_p) {
  const int g = blockIdx.x * 64 + threadIdx.x;  // 16384 = B * D * N
  const int b = g >> 13;
  const int dn = g & 8191;
  const float beta = 1.f / (1.f + __expf(-beta_p[0]));
  const float A2 = -__expf(A_log[dn]) * LOG2E;
  float bL = beta;
#pragma unroll
  for (int i = 0; i < 4; ++i) bL *= bL;  // beta^16 = beta^LCH

  const size_t cs = (size_t)D_IN * D_ST;
  const size_t base = (size_t)b * NCH * cs + dn;
  const size_t sbase = (size_t)b * NCH * D_IN + (dn >> 4);

  float hg[8], vg[8], cg[8], sg[8];
#pragma unroll
  for (int i = 0; i < 8; ++i) {
    hg[i] = (float)hh[base + i * cs];
    vg[i] = (float)vh[base + i * cs];
    cg[i] = (float)cvv[base + i * cs];
    sg[i] = sdt[sbase + i * D_IN];
  }
  float H = 0.f, V = 0.f;
  for (int c0 = 0; c0 < NCH; c0 += 8) {
    const int cp = (c0 + 8) & (NCH - 1);  // wraps; last prefetch unused
    float hn[8], vn[8], cn[8], sn[8];
#pragma unroll
    for (int i = 0; i < 8; ++i) {
      hn[i] = (float)hh[base + (size_t)(cp + i) * cs];
      vn[i] = (float)vh[base + (size_t)(cp + i) * cs];
      cn[i] = (float)cvv[base + (size_t)(cp + i) * cs];
      sn[i] = sdt[sbase + (size_t)(cp + i) * D_IN];
    }
#pragma unroll
    for (int i = 0; i < 8; ++i) {
      hh[base + (size_t)(c0 + i) * cs] = (f16)H;
      vh[base + (size_t)(c0 + i) * cs] = (f16)V;
      const float Pa = fast_exp2(sg[i] * A2);
      const float Hn = fmaf(Pa, H, fmaf(cg[i], V, hg[i]));
      V = fmaf(bL, V, vg[i]);
      H = Hn;
    }
#pragma unroll
    for (int i = 0; i < 8; ++i) { hg[i] = hn[i]; vg[i] = vn[i]; cg[i] = cn[i]; sg[i] = sn[i]; }
  }
}

// ---------------- pass 2: read dt(fp16)+x, correct-init scan, emit y ---------
#define S2_BODY(GET_A)                                        \
  _Pragma("unroll")                                           \
  for (int j = 0; j < LCH; ++j) {                             \
    const float dtc = dtv[j], xv = xs[j];                     \
    const float u = alpha * dtc * xv;                         \
    GET_A;                                                    \
    float4 Bq[8];                                             \
    _Pragma("unroll")                                         \
    for (int i = 0; i < 8; ++i) Bq[i] = ((const float4*)&Ps[j][DTR])[i]; \
    const float* Bf = (const float*)Bq;                       \
    float y0 = 0.f, y1 = 0.f, y2 = 0.f, y3 = 0.f;             \
    float ar = 1.f;                                           \
    _Pragma("unroll")                                         \
    for (int n = 0; n < 16; ++n) {                            \
      NEXT_A(ar, n);                                          \
      v[n] = fmaf(beta, v[n], u * Bf[n]);                     \
      h[n] = fmaf(ar, h[n], v[n]);                            \
      float hc = h[n] * Bf[16 + n];                           \
      if ((n & 3) == 0) y0 += hc;                             \
      else if ((n & 3) == 1) y1 += hc;                        \
      else if ((n & 3) == 2) y2 += hc;                        \
      else y3 += hc;                                          \
    }                                                         \
    op[(size_t)j * D_IN] = (y0 + y1) + (y2 + y3) + Dv * xv;   \
  }

__global__ __launch_bounds__(256) void k_scan2(const float* __restrict__ x,
                                               const f16* __restrict__ dth,
                                               const float* __restrict__ proj,
                                               const float* __restrict__ A_log,
                                               const float* __restrict__ D_param,
                                               const float* __restrict__ alpha_p,
                                               const float* __restrict__ beta_p,
                                               const f16* __restrict__ hh,
                                               const f16* __restrict__ vh,
                                               float* __restrict__ out) {
  __shared__ float Ps[LCH][PDIM];
  const int c = blockIdx.x, b = blockIdx.z;
  const int d = blockIdx.y * 256 + threadIdx.x;
  const int t0 = c * LCH;
  {
    const float4* src = (const float4*)(proj + ((size_t)b * LSEQ + t0) * PDIM);
    ((float4*)&Ps[0][0])[threadIdx.x] = src[threadIdx.x];
  }
  float xs[LCH], dtv[LCH];
  {
    const float* xp = x + ((size_t)b * LSEQ + t0) * D_IN + d;
    const f16* dp = dth + ((size_t)b * LSEQ + t0) * D_IN + d;
#pragma unroll
    for (int j = 0; j < LCH; ++j) xs[j] = xp[(size_t)j * D_IN];
#pragma unroll
    for (int j = 0; j < LCH; ++j) dtv[j] = (float)dp[(size_t)j * D_IN];
  }
  const float alpha = alpha_p[0];
  const float beta = 1.f / (1.f + __expf(-beta_p[0]));
  const float Dv = D_param[d];
  float A2[D_ST];
  const bool powA = loadA2(A_log, d, A2);
  const size_t ibase = ((size_t)(b * NCH + c) * D_IN + d) * D_ST;
  float h[16], v[16];
  ld16h(hh + ibase, h);
  ld16h(vh + ibase, v);
  __syncthreads();

  float* op = out + ((size_t)b * LSEQ + t0) * D_IN + d;
  if (powA) {
#define NEXT_A(ar, n) ar *= r
    S2_BODY(const float r = fast_exp2(dtc * A2[0]))
#undef NEXT_A
  } else {
#define NEXT_A(ar, n) ar = fast_exp2(dtc * A2[n])
    S2_BODY()
#undef NEXT_A
  }
}

extern "C" void kernel_launch(void* const* d_in, const int* in_sizes, int n_in,
                              void* d_out, int out_size, void* d_ws, size_t ws_size,
                              hipStream_t stream) {
  const float* x = (const float*)d_in[0];
  const float* A_log = (const float*)d_in[1];
  const float* D_param = (const float*)d_in[2];
  const float* W_xproj = (const float*)d_in[3];
  const float* W_dt = (const float*)d_in[4];
  const float* b_dt = (const float*)d_in[5];
  const float* alpha = (const float*)d_in[6];
  const float* beta_logit = (const float*)d_in[7];
  float* out = (float*)d_out;

  const size_t NST = (size_t)BSZ * NCH * D_IN * D_ST;  // 4194304
  float* ws = (float*)d_ws;
  float* proj = ws;                                  // 524288 floats
  float* sdt = proj + (size_t)BSZ * LSEQ * PDIM;     // 262144 floats
  f16* hh = (f16*)(sdt + (size_t)BSZ * NCH * D_IN);  // 4194304 halves
  f16* vh = hh + NST;
  f16* cvv = vh + NST;
  f16* dth = cvv + NST;                              // B*L*D halves
  short* Whi = (short*)(dth + (size_t)BSZ * LSEQ * D_IN);
  short* Wlo = Whi + (size_t)PDIM * D_IN;            // total ~37 MB

  k_wprep<<<dim3(PDIM * D_IN / 1024), dim3(256), 0, stream>>>(W_xproj, Whi, Wlo);
  k_proj<<<dim3(BSZ * LSEQ / 16), dim3(64), 0, stream>>>(x, Whi, Wlo, proj);
  k_scan1<<<dim3(NCH, D_IN / 256, BSZ), dim3(256), 0, stream>>>(
      x, proj, A_log, W_dt, b_dt, alpha, beta_logit, hh, vh, cvv, sdt, dth);
  k_fix<<<dim3(BSZ * D_IN * D_ST / 64), dim3(64), 0, stream>>>(hh, vh, cvv, sdt, A_log,
                                                               beta_logit);
  k_scan2<<<dim3(NCH, D_IN / 256, BSZ), dim3(256), 0, stream>>>(
      x, dth, proj, A_log, D_param, alpha, beta_logit, hh, vh, out);
}